// Round 3
// baseline (397.753 us; speedup 1.0000x reference)
//
#include <hip/hip_runtime.h>
#include <hip/hip_bf16.h>
#include <math.h>

// ---------------------------------------------------------------------------
// Round 3: latency-bound attn fix.
//  - attn: 1 wave/block, 2048 blocks, XCD-swizzled, barrier-free, K/V frags
//    read direct from L2, per-wave LDS P only, exp2-domain softmax + defer-max.
//  - bn_finalize inlined into all consumers; casts fused; qkv_post+v_transpose
//    fused. merge/fc2 GEMMs get 64-row tiles (384 blocks instead of 192).
// Layouts: activations row-major [row = b*1024+pix][ch]; qk_bf [row][512]
// (per head: 32 q pre-scaled by invsqrt(32)*log2e, 32 k); vt [b*8+h][128][1024].
// MFMA 16x16x32_bf16, C/D: col=lane&15, row=(lane>>4)*4+reg (m89).
// ---------------------------------------------------------------------------

#define NPIX 1024
typedef __attribute__((ext_vector_type(8))) short short8;
typedef __attribute__((ext_vector_type(4))) float f32x4;
typedef unsigned long long ull;

__device__ __forceinline__ float gelu_exact(float v) {
    return 0.5f * v * (1.0f + erff(v * 0.70710678118654752f));
}
__device__ __forceinline__ short f2bf(float f) {   // RNE float->bf16
    unsigned u = __float_as_uint(f);
    unsigned r = (u + 0x7fffu + ((u >> 16) & 1u)) >> 16;
    return (short)r;
}
__device__ __forceinline__ ull pack4bf(float a, float b, float c, float d) {
    return  (ull)(unsigned short)f2bf(a)
         | ((ull)(unsigned short)f2bf(b) << 16)
         | ((ull)(unsigned short)f2bf(c) << 32)
         | ((ull)(unsigned short)f2bf(d) << 48);
}
// BN finalize math from raw sums (per-channel): returns scale, shift
__device__ __forceinline__ void bn_sc(float s, float ss, float g, float bt,
                                      float& sc, float& sh) {
    float mean = s * (1.0f / 8192.0f);
    float var  = ss * (1.0f / 8192.0f) - mean * mean;
    sc = g * rsqrtf(var + 1e-5f);
    sh = bt - mean * sc;
}

// ---------------------------------------------------------------------------
// fused weight casts (all four weight matrices in one launch)
// ---------------------------------------------------------------------------
__global__ __launch_bounds__(256) void cast4(
    const float* __restrict__ s0, const float* __restrict__ s1,
    const float* __restrict__ s2, const float* __restrict__ s3,
    short* __restrict__ d0, short* __restrict__ d1,
    short* __restrict__ d2, short* __restrict__ d3)
{
    int t = blockIdx.x * 256 + threadIdx.x;      // 196608 total
    const float* s; short* d; int off;
    if (t < 73728)       { s = s0; d = d0; off = t; }
    else if (t < 122880) { s = s1; d = d1; off = t - 73728; }
    else if (t < 159744) { s = s2; d = d2; off = t - 122880; }
    else                 { s = s3; d = d3; off = t - 159744; }
    float4 a = *(const float4*)&s[(size_t)off * 8];
    float4 b = *(const float4*)&s[(size_t)off * 8 + 4];
    *(ull*)&d[(size_t)off * 8]     = pack4bf(a.x, a.y, a.z, a.w);
    *(ull*)&d[(size_t)off * 8 + 4] = pack4bf(b.x, b.y, b.z, b.w);
}

// ---------------------------------------------------------------------------
// x (B,C,N) fp32 -> x_bf [row][384] bf16 + x_tf [row][384] fp32 (transpose)
// ---------------------------------------------------------------------------
__global__ __launch_bounds__(256) void x_transpose(
    const float* __restrict__ x, short* __restrict__ x_bf, float* __restrict__ x_tf)
{
    __shared__ float ls[64][65];
    const int b = blockIdx.z, c0 = blockIdx.y * 64, n0 = blockIdx.x * 64;
    const int rl = threadIdx.x >> 6, ll = threadIdx.x & 63;
    #pragma unroll
    for (int it = 0; it < 16; ++it) {
        int c = rl + it * 4;
        ls[c][ll] = x[((size_t)b * 384 + c0 + c) * NPIX + n0 + ll];
    }
    __syncthreads();
    #pragma unroll
    for (int it = 0; it < 16; ++it) {
        int n = rl + it * 4;
        float v = ls[ll][n];
        size_t row = (size_t)b * NPIX + n0 + n;
        x_tf[row * 384 + c0 + ll] = v;
        x_bf[row * 384 + c0 + ll] = f2bf(v);
    }
}

// ---------------------------------------------------------------------------
// GEMM bf16 MFMA: D[row][o] = sum_k A[row][k] * Wt[o][k], fp32 out.
// Tile BM x 128, BK=64, 4 waves, fused BN-stat atomics. BM = NAF*32.
// ---------------------------------------------------------------------------
template<int NAF>
__global__ __launch_bounds__(256) void gemm_bf16(
    const short* __restrict__ A, const short* __restrict__ Wt,
    float* __restrict__ D, float* __restrict__ sums, int O, int K)
{
    constexpr int BM = NAF * 32;
    __shared__ short a_s[BM * 72];
    __shared__ short w_s[128 * 72];
    const int tid = threadIdx.x;
    const int wave = tid >> 6, lane = tid & 63;
    const int l16 = lane & 15, lhi = lane >> 4;
    const int m0 = blockIdx.x * BM, o0 = blockIdx.y * 128;
    const int wm = (wave & 1) * (BM / 2), wo = (wave >> 1) * 64;

    f32x4 acc[NAF][4];
    #pragma unroll
    for (int i = 0; i < NAF; ++i)
        #pragma unroll
        for (int j = 0; j < 4; ++j) acc[i][j] = (f32x4){0.f, 0.f, 0.f, 0.f};

    for (int k0 = 0; k0 < K; k0 += 64) {
        #pragma unroll
        for (int it = 0; it < NAF; ++it) {
            int idx = tid + it * 256;
            int r = idx >> 3, ch = idx & 7;
            *(float4*)&a_s[r * 72 + ch * 8] =
                *(const float4*)&A[(size_t)(m0 + r) * K + k0 + ch * 8];
        }
        #pragma unroll
        for (int it = 0; it < 4; ++it) {
            int idx = tid + it * 256;
            int r = idx >> 3, ch = idx & 7;
            *(float4*)&w_s[r * 72 + ch * 8] =
                *(const float4*)&Wt[(size_t)(o0 + r) * K + k0 + ch * 8];
        }
        __syncthreads();
        #pragma unroll
        for (int kb = 0; kb < 2; ++kb) {
            short8 af[NAF], wf[4];
            #pragma unroll
            for (int i = 0; i < NAF; ++i)
                af[i] = *(const short8*)&a_s[(wm + i * 16 + l16) * 72 + kb * 32 + lhi * 8];
            #pragma unroll
            for (int j = 0; j < 4; ++j)
                wf[j] = *(const short8*)&w_s[(wo + j * 16 + l16) * 72 + kb * 32 + lhi * 8];
            #pragma unroll
            for (int i = 0; i < NAF; ++i)
                #pragma unroll
                for (int j = 0; j < 4; ++j)
                    acc[i][j] = __builtin_amdgcn_mfma_f32_16x16x32_bf16(af[i], wf[j], acc[i][j], 0, 0, 0);
        }
        __syncthreads();
    }

    #pragma unroll
    for (int i = 0; i < NAF; ++i) {
        #pragma unroll
        for (int r = 0; r < 4; ++r) {
            size_t row = (size_t)(m0 + wm + i * 16 + lhi * 4 + r);
            #pragma unroll
            for (int j = 0; j < 4; ++j)
                D[row * O + o0 + wo + j * 16 + l16] = acc[i][j][r];
        }
    }
    #pragma unroll
    for (int j = 0; j < 4; ++j) {
        float s1 = 0.f, s2 = 0.f;
        #pragma unroll
        for (int i = 0; i < NAF; ++i)
            #pragma unroll
            for (int r = 0; r < 4; ++r) { float v = acc[i][j][r]; s1 += v; s2 += v * v; }
        s1 += __shfl_xor(s1, 16); s1 += __shfl_xor(s1, 32);
        s2 += __shfl_xor(s2, 16); s2 += __shfl_xor(s2, 32);
        if (lhi == 0) {
            int col = o0 + wo + j * 16 + l16;
            atomicAdd(&sums[col * 2], s1);
            atomicAdd(&sums[col * 2 + 1], s2);
        }
    }
}

// ---------------------------------------------------------------------------
// Fused qkv post: BN-finalize inline; q/k -> qk_bf [row][512] (q pre-scaled by
// invsqrt(32)*log2e); v -> BN + transpose -> vt [b*8+h][128][1024].
// grid (16 n-tiles, 4 head-pairs, 8 b), 256 threads.
// ---------------------------------------------------------------------------
__global__ __launch_bounds__(256) void qkv_post_vt(
    const float* __restrict__ raw, const float* __restrict__ sums,
    const float* __restrict__ gamma, const float* __restrict__ beta,
    short* __restrict__ qko, short* __restrict__ vto)
{
    __shared__ short ls[64][136];
    const int b = blockIdx.z, hp = blockIdx.y, n0 = blockIdx.x * 64;
    const int tid = threadIdx.x;
    const int r = tid >> 2, cg = tid & 3;
    const size_t rowbase = (size_t)(b * NPIX + n0 + r) * 1536;
    const float qs = 0.17677669529663687f * 1.4426950408889634f;  // 1/sqrt(32)*log2e

    {   // q/k columns
        int hh = 2 * hp + (cg >> 1);
        int chb = hh * 192 + (cg & 1) * 32;
        bool isq = (cg & 1) == 0;
        size_t orow = (size_t)(b * NPIX + n0 + r) * 512 + hp * 128 + cg * 32;
        #pragma unroll
        for (int cc = 0; cc < 8; ++cc) {
            int ch = chb + cc * 4;
            float4 v  = *(const float4*)&raw[rowbase + ch];
            float4 s1 = *(const float4*)&sums[ch * 2];
            float4 s2 = *(const float4*)&sums[ch * 2 + 4];
            float4 gg = *(const float4*)&gamma[ch];
            float4 bb = *(const float4*)&beta[ch];
            float sc, sh, o[4];
            bn_sc(s1.x, s1.y, gg.x, bb.x, sc, sh); o[0] = v.x * sc + sh;
            bn_sc(s1.z, s1.w, gg.y, bb.y, sc, sh); o[1] = v.y * sc + sh;
            bn_sc(s2.x, s2.y, gg.z, bb.z, sc, sh); o[2] = v.z * sc + sh;
            bn_sc(s2.z, s2.w, gg.w, bb.w, sc, sh); o[3] = v.w * sc + sh;
            if (isq) { o[0] *= qs; o[1] *= qs; o[2] *= qs; o[3] *= qs; }
            *(ull*)&qko[orow + cc * 4] = pack4bf(o[0], o[1], o[2], o[3]);
        }
    }
    #pragma unroll
    for (int hv = 0; hv < 2; ++hv) {
        int h = 2 * hp + hv;
        __syncthreads();
        #pragma unroll
        for (int cc = 0; cc < 8; ++cc) {
            int ch = h * 192 + 64 + cg * 32 + cc * 4;
            float4 v  = *(const float4*)&raw[rowbase + ch];
            float4 s1 = *(const float4*)&sums[ch * 2];
            float4 s2 = *(const float4*)&sums[ch * 2 + 4];
            float4 gg = *(const float4*)&gamma[ch];
            float4 bb = *(const float4*)&beta[ch];
            float sc, sh, o[4];
            bn_sc(s1.x, s1.y, gg.x, bb.x, sc, sh); o[0] = v.x * sc + sh;
            bn_sc(s1.z, s1.w, gg.y, bb.y, sc, sh); o[1] = v.y * sc + sh;
            bn_sc(s2.x, s2.y, gg.z, bb.z, sc, sh); o[2] = v.z * sc + sh;
            bn_sc(s2.z, s2.w, gg.w, bb.w, sc, sh); o[3] = v.w * sc + sh;
            *(ull*)&ls[r][cg * 32 + cc * 4] = pack4bf(o[0], o[1], o[2], o[3]);
        }
        __syncthreads();
        int dv = tid >> 1, nh = tid & 1;
        size_t obase = ((size_t)(b * 8 + h) * 128 + dv) * NPIX + n0 + nh * 32;
        #pragma unroll
        for (int j = 0; j < 8; ++j) {
            int n = nh * 32 + j * 4;
            ull u =  (ull)(unsigned short)ls[n][dv]
                  | ((ull)(unsigned short)ls[n + 1][dv] << 16)
                  | ((ull)(unsigned short)ls[n + 2][dv] << 32)
                  | ((ull)(unsigned short)ls[n + 3][dv] << 48);
            *(ull*)&vto[obase + j * 4] = u;
        }
    }
}

// ---------------------------------------------------------------------------
// Barrier-free flash attention. 1 wave/block, 32 q rows/wave, 2048 blocks,
// XCD-swizzled so each XCD owns 8 (b,h) pairs (V stays L2-resident).
// K/V fragments read direct from global; LDS only for per-wave P.
// Softmax in exp2 domain (q pre-scaled by log2e); defer-max THR=11 (log2).
// ---------------------------------------------------------------------------
__global__ __launch_bounds__(64) void attn_kernel(
    const short* __restrict__ qk, const short* __restrict__ vt, short* __restrict__ outp)
{
    __shared__ short pw[32 * 72];
    const int id0 = blockIdx.x;                       // 2048
    const int swz = (id0 & 7) * 256 + (id0 >> 3);     // XCD-contiguous chunks
    const int qt = swz & 31, bh = swz >> 5;
    const int h = bh & 7, b = bh >> 3;
    const int q0 = qt * 32;
    const int lane = threadIdx.x;
    const int l16 = lane & 15, lhi = lane >> 4;

    const short* qkb = qk + (size_t)b * NPIX * 512 + h * 64;
    const short* vb  = vt + (size_t)bh * 128 * NPIX;

    short8 qf[2];
    qf[0] = *(const short8*)&qkb[(size_t)(q0 + l16) * 512 + lhi * 8];
    qf[1] = *(const short8*)&qkb[(size_t)(q0 + 16 + l16) * 512 + lhi * 8];

    f32x4 acc[2][8];
    #pragma unroll
    for (int i = 0; i < 2; ++i)
        #pragma unroll
        for (int j = 0; j < 8; ++j) acc[i][j] = (f32x4){0.f, 0.f, 0.f, 0.f};
    float m_run[2][4], l_run[2][4];
    #pragma unroll
    for (int i = 0; i < 2; ++i)
        #pragma unroll
        for (int r = 0; r < 4; ++r) { m_run[i][r] = -1e30f; l_run[i][r] = 0.f; }

    for (int mt = 0; mt < 16; ++mt) {
        const int m0 = mt * 64;
        short8 kf[4];
        #pragma unroll
        for (int fm = 0; fm < 4; ++fm)
            kf[fm] = *(const short8*)&qkb[(size_t)(m0 + fm * 16 + l16) * 512 + 32 + lhi * 8];

        f32x4 s[2][4];
        #pragma unroll
        for (int i = 0; i < 2; ++i)
            #pragma unroll
            for (int j = 0; j < 4; ++j) s[i][j] = (f32x4){0.f, 0.f, 0.f, 0.f};
        #pragma unroll
        for (int fm = 0; fm < 4; ++fm)
            #pragma unroll
            for (int fq = 0; fq < 2; ++fq)
                s[fq][fm] = __builtin_amdgcn_mfma_f32_16x16x32_bf16(qf[fq], kf[fm], s[fq][fm], 0, 0, 0);

        // tile row-max (reduce over fm regs + 16 lanes)
        float mx[2][4];
        bool need = false;
        #pragma unroll
        for (int fq = 0; fq < 2; ++fq)
            #pragma unroll
            for (int rr = 0; rr < 4; ++rr) {
                float m1 = fmaxf(fmaxf(s[fq][0][rr], s[fq][1][rr]),
                                 fmaxf(s[fq][2][rr], s[fq][3][rr]));
                m1 = fmaxf(m1, __shfl_xor(m1, 1));
                m1 = fmaxf(m1, __shfl_xor(m1, 2));
                m1 = fmaxf(m1, __shfl_xor(m1, 4));
                m1 = fmaxf(m1, __shfl_xor(m1, 8));
                mx[fq][rr] = m1;
                need |= (m1 > m_run[fq][rr] + 11.0f);
            }
        if (__any(need)) {   // rescale path (rare after tile 0)
            #pragma unroll
            for (int fq = 0; fq < 2; ++fq)
                #pragma unroll
                for (int rr = 0; rr < 4; ++rr) {
                    float mn = fmaxf(m_run[fq][rr], mx[fq][rr]);
                    float f = exp2f(m_run[fq][rr] - mn);
                    m_run[fq][rr] = mn;
                    l_run[fq][rr] *= f;
                    #pragma unroll
                    for (int fdv = 0; fdv < 8; ++fdv) acc[fq][fdv][rr] *= f;
                }
        }
        // P = exp2(s - m), write to per-wave LDS, accumulate l
        #pragma unroll
        for (int fq = 0; fq < 2; ++fq)
            #pragma unroll
            for (int rr = 0; rr < 4; ++rr) {
                float mr = m_run[fq][rr];
                float rsum = 0.f;
                #pragma unroll
                for (int fm = 0; fm < 4; ++fm) {
                    float p = exp2f(s[fq][fm][rr] - mr);
                    rsum += p;
                    pw[(fq * 16 + lhi * 4 + rr) * 72 + fm * 16 + l16] = f2bf(p);
                }
                rsum += __shfl_xor(rsum, 1);
                rsum += __shfl_xor(rsum, 2);
                rsum += __shfl_xor(rsum, 4);
                rsum += __shfl_xor(rsum, 8);
                l_run[fq][rr] += rsum;
            }
        asm volatile("s_waitcnt lgkmcnt(0)" ::: "memory");   // P visible to wave

        // PV: acc[fq][fdv] += P * V^T
        #pragma unroll
        for (int kc = 0; kc < 2; ++kc) {
            short8 pf0 = *(const short8*)&pw[(l16) * 72 + kc * 32 + lhi * 8];
            short8 pf1 = *(const short8*)&pw[(16 + l16) * 72 + kc * 32 + lhi * 8];
            #pragma unroll
            for (int fdv = 0; fdv < 8; ++fdv) {
                short8 vf = *(const short8*)&vb[(size_t)(fdv * 16 + l16) * NPIX + m0 + kc * 32 + lhi * 8];
                acc[0][fdv] = __builtin_amdgcn_mfma_f32_16x16x32_bf16(pf0, vf, acc[0][fdv], 0, 0, 0);
                acc[1][fdv] = __builtin_amdgcn_mfma_f32_16x16x32_bf16(pf1, vf, acc[1][fdv], 0, 0, 0);
            }
        }
    }

    #pragma unroll
    for (int fq = 0; fq < 2; ++fq)
        #pragma unroll
        for (int rr = 0; rr < 4; ++rr) {
            float inv = 1.0f / l_run[fq][rr];
            size_t row = (size_t)b * NPIX + q0 + fq * 16 + lhi * 4 + rr;
            #pragma unroll
            for (int fdv = 0; fdv < 8; ++fdv) {
                float o = acc[fq][fdv][rr] * inv;
                outp[row * 1024 + h * 128 + fdv * 16 + l16] = f2bf(gelu_exact(o));
            }
        }
}

// ---------------------------------------------------------------------------
// x2 = x_tf + bn(merge_raw); writes fp32 + bf16. BN finalize inline.
// ---------------------------------------------------------------------------
__global__ __launch_bounds__(256) void x2_kernel(
    const float* __restrict__ raw, const float* __restrict__ sums,
    const float* __restrict__ gamma, const float* __restrict__ beta,
    const float* __restrict__ xtf, float* __restrict__ x2f, short* __restrict__ x2bf)
{
    int t = blockIdx.x * 256 + threadIdx.x;     // ROWS*96
    int row = t / 96, c = (t % 96) * 4;
    size_t idx = (size_t)row * 384 + c;
    float4 v  = *(const float4*)&raw[idx];
    float4 xr = *(const float4*)&xtf[idx];
    float4 s1 = *(const float4*)&sums[c * 2];
    float4 s2 = *(const float4*)&sums[c * 2 + 4];
    float4 gg = *(const float4*)&gamma[c];
    float4 bb = *(const float4*)&beta[c];
    float sc, sh;
    bn_sc(s1.x, s1.y, gg.x, bb.x, sc, sh); float o0 = xr.x + v.x * sc + sh;
    bn_sc(s1.z, s1.w, gg.y, bb.y, sc, sh); float o1 = xr.y + v.y * sc + sh;
    bn_sc(s2.x, s2.y, gg.z, bb.z, sc, sh); float o2 = xr.z + v.z * sc + sh;
    bn_sc(s2.z, s2.w, gg.w, bb.w, sc, sh); float o3 = xr.w + v.w * sc + sh;
    *(float4*)&x2f[idx] = make_float4(o0, o1, o2, o3);
    *(ull*)&x2bf[idx] = pack4bf(o0, o1, o2, o3);
}

// ---------------------------------------------------------------------------
// h = gelu(bn(fc1_raw)) -> bf16. BN finalize inline.
// ---------------------------------------------------------------------------
__global__ __launch_bounds__(256) void h_kernel(
    const float* __restrict__ raw, const float* __restrict__ sums,
    const float* __restrict__ gamma, const float* __restrict__ beta,
    short* __restrict__ hbf)
{
    int t = blockIdx.x * 256 + threadIdx.x;     // ROWS*192
    int row = t / 192, c = (t % 192) * 4;
    size_t idx = (size_t)row * 768 + c;
    float4 v  = *(const float4*)&raw[idx];
    float4 s1 = *(const float4*)&sums[c * 2];
    float4 s2 = *(const float4*)&sums[c * 2 + 4];
    float4 gg = *(const float4*)&gamma[c];
    float4 bb = *(const float4*)&beta[c];
    float sc, sh;
    bn_sc(s1.x, s1.y, gg.x, bb.x, sc, sh); float o0 = gelu_exact(v.x * sc + sh);
    bn_sc(s1.z, s1.w, gg.y, bb.y, sc, sh); float o1 = gelu_exact(v.y * sc + sh);
    bn_sc(s2.x, s2.y, gg.z, bb.z, sc, sh); float o2 = gelu_exact(v.z * sc + sh);
    bn_sc(s2.z, s2.w, gg.w, bb.w, sc, sh); float o3 = gelu_exact(v.w * sc + sh);
    *(ull*)&hbf[idx] = pack4bf(o0, o1, o2, o3);
}

// ---------------------------------------------------------------------------
// out[b][c][n] = x2f[row][c] + bn(fc2_raw[row][c]) (transposed store), inline BN.
// ---------------------------------------------------------------------------
__global__ __launch_bounds__(256) void final_tr(
    const float* __restrict__ raw, const float* __restrict__ sums,
    const float* __restrict__ gamma, const float* __restrict__ beta,
    const float* __restrict__ x2f, float* __restrict__ out)
{
    __shared__ float ls[64][65];
    const int b = blockIdx.z, c0 = blockIdx.y * 64, n0 = blockIdx.x * 64;
    const int rl = threadIdx.x >> 6, ll = threadIdx.x & 63;
    const int c = c0 + ll;
    float sc, sh;
    bn_sc(sums[c * 2], sums[c * 2 + 1], gamma[c], beta[c], sc, sh);
    #pragma unroll
    for (int it = 0; it < 16; ++it) {
        int n = rl + it * 4;
        size_t idx = ((size_t)b * NPIX + n0 + n) * 384 + c;
        ls[n][ll] = x2f[idx] + raw[idx] * sc + sh;
    }
    __syncthreads();
    #pragma unroll
    for (int it = 0; it < 16; ++it) {
        int cr = rl + it * 4;
        out[((size_t)b * 384 + c0 + cr) * NPIX + n0 + ll] = ls[ll][cr];
    }
}

// ---------------------------------------------------------------------------
extern "C" void kernel_launch(void* const* d_in, const int* in_sizes, int n_in,
                              void* d_out, int out_size, void* d_ws, size_t ws_size,
                              hipStream_t stream)
{
    const float* x       = (const float*)d_in[0];
    const float* w_qkv   = (const float*)d_in[1];
    const float* g_qkv   = (const float*)d_in[2];
    const float* b_qkv   = (const float*)d_in[3];
    const float* w_merge = (const float*)d_in[4];
    const float* g_merge = (const float*)d_in[5];
    const float* b_merge = (const float*)d_in[6];
    const float* w_fc1   = (const float*)d_in[7];
    const float* g_fc1   = (const float*)d_in[8];
    const float* b_fc1   = (const float*)d_in[9];
    const float* w_fc2   = (const float*)d_in[10];
    const float* g_fc2   = (const float*)d_in[11];
    const float* b_fc2   = (const float*)d_in[12];
    float* out = (float*)d_out;

    char* ws = (char*)d_ws;
    short* wq_bf   = (short*)(ws + 0);            // 1,179,648 B
    short* wm_bf   = (short*)(ws + 1179648);      //   786,432
    short* wf1_bf  = (short*)(ws + 1966080);      //   589,824
    short* wf2_bf  = (short*)(ws + 2555904);      //   589,824
    short* x_bf    = (short*)(ws + 3145728);      // 6,291,456
    float* x_tf    = (float*)(ws + 9437184);      // 12,582,912
    float* qkv_raw = (float*)(ws + 22020096);     // 50,331,648 (dead after qkv_post_vt)
    short* qk_bf   = (short*)(ws + 72351744);     // 8,388,608
    short* vt      = (short*)(ws + 80740352);     // 16,777,216
    short* attn_bf = (short*)(ws + 22020096);     // 16,777,216 (reuse qkv_raw)
    float* fc1_raw = (float*)(ws + 38797312);     // 25,165,824 (reuse qkv_raw tail)
    float* fc2_raw = (float*)(ws + 22020096);     // 12,582,912 (reuse attn_bf, dead then)
    short* h_bf    = (short*)(ws + 80740352);     // 12,582,912 (reuse vt, dead then)
    float* merge_raw = (float*)(ws + 97517568);   // 12,582,912
    short* x2_bf   = (short*)(ws + 110100480);    // 6,291,456
    float* x2_f    = (float*)(ws + 116391936);    // 12,582,912
    float* sums    = (float*)(ws + 128974848);    // 3072 ch * 2 = 24,576 B

    float* sums_qkv = sums;
    float* sums_mg  = sums + 1536 * 2;
    float* sums_f1  = sums + (1536 + 384) * 2;
    float* sums_f2  = sums + (1536 + 384 + 768) * 2;

    hipMemsetAsync(sums, 0, 3072 * 2 * sizeof(float), stream);

    cast4<<<768, 256, 0, stream>>>(w_qkv, w_merge, w_fc1, w_fc2,
                                   wq_bf, wm_bf, wf1_bf, wf2_bf);
    x_transpose<<<dim3(16, 6, 8), 256, 0, stream>>>(x, x_bf, x_tf);

    gemm_bf16<4><<<dim3(64, 12), 256, 0, stream>>>(x_bf, wq_bf, qkv_raw, sums_qkv, 1536, 384);
    qkv_post_vt<<<dim3(16, 4, 8), 256, 0, stream>>>(qkv_raw, sums_qkv, g_qkv, b_qkv, qk_bf, vt);

    attn_kernel<<<2048, 64, 0, stream>>>(qk_bf, vt, attn_bf);

    gemm_bf16<2><<<dim3(128, 3), 256, 0, stream>>>(attn_bf, wm_bf, merge_raw, sums_mg, 384, 1024);
    x2_kernel<<<3072, 256, 0, stream>>>(merge_raw, sums_mg, g_merge, b_merge, x_tf, x2_f, x2_bf);

    gemm_bf16<4><<<dim3(64, 6), 256, 0, stream>>>(x2_bf, wf1_bf, fc1_raw, sums_f1, 768, 384);
    h_kernel<<<6144, 256, 0, stream>>>(fc1_raw, sums_f1, g_fc1, b_fc1, h_bf);

    gemm_bf16<2><<<dim3(128, 3), 256, 0, stream>>>(h_bf, wf2_bf, fc2_raw, sums_f2, 384, 768);
    final_tr<<<dim3(16, 6, 8), 256, 0, stream>>>(fc2_raw, sums_f2, g_fc2, b_fc2, x2_f, out);
}

// Round 4
// 342.836 us; speedup vs baseline: 1.1602x; 1.1602x over previous
//
#include <hip/hip_runtime.h>
#include <hip/hip_bf16.h>
#include <math.h>

// ---------------------------------------------------------------------------
// Round 4: shorten attn's per-wave critical path.
//  - Swapped QK^T (mfma(K,Q)): row-softmax reduce = in-lane + 2 shfl (was 8/row);
//    P store = 8 ds_write_b64 (was 32 b16); m/l = 2 scalars/lane (was 8).
//  - V-fragment + next-K register prefetch issued before softmax.
//  - Revert round-3 regressions: bn_finalize separate (no per-element rsqrt),
//    all GEMMs 128x128.
// Layouts: activations row-major [row=b*1024+pix][ch]; qk_bf [row][512]
// (head h: q at h*64 pre-scaled by invsqrt(32)*log2e, k at h*64+32);
// vt [(b*8+h)][128][1024].
// MFMA 16x16x32_bf16: A/B row = lane&15, k=(lane>>4)*8+j;
// C/D col=lane&15, row=(lane>>4)*4+reg (m89).
// ---------------------------------------------------------------------------

#define NPIX 1024
typedef __attribute__((ext_vector_type(8))) short short8;
typedef __attribute__((ext_vector_type(4))) float f32x4;
typedef unsigned long long ull;

__device__ __forceinline__ float gelu_exact(float v) {
    return 0.5f * v * (1.0f + erff(v * 0.70710678118654752f));
}
__device__ __forceinline__ short f2bf(float f) {   // RNE float->bf16
    unsigned u = __float_as_uint(f);
    unsigned r = (u + 0x7fffu + ((u >> 16) & 1u)) >> 16;
    return (short)r;
}
__device__ __forceinline__ ull pack4bf(float a, float b, float c, float d) {
    return  (ull)(unsigned short)f2bf(a)
         | ((ull)(unsigned short)f2bf(b) << 16)
         | ((ull)(unsigned short)f2bf(c) << 32)
         | ((ull)(unsigned short)f2bf(d) << 48);
}

// ---------------------------------------------------------------------------
__global__ __launch_bounds__(256) void cast4(
    const float* __restrict__ s0, const float* __restrict__ s1,
    const float* __restrict__ s2, const float* __restrict__ s3,
    short* __restrict__ d0, short* __restrict__ d1,
    short* __restrict__ d2, short* __restrict__ d3)
{
    int t = blockIdx.x * 256 + threadIdx.x;      // 196608 total
    const float* s; short* d; int off;
    if (t < 73728)       { s = s0; d = d0; off = t; }
    else if (t < 122880) { s = s1; d = d1; off = t - 73728; }
    else if (t < 159744) { s = s2; d = d2; off = t - 122880; }
    else                 { s = s3; d = d3; off = t - 159744; }
    float4 a = *(const float4*)&s[(size_t)off * 8];
    float4 b = *(const float4*)&s[(size_t)off * 8 + 4];
    *(ull*)&d[(size_t)off * 8]     = pack4bf(a.x, a.y, a.z, a.w);
    *(ull*)&d[(size_t)off * 8 + 4] = pack4bf(b.x, b.y, b.z, b.w);
}

// ---------------------------------------------------------------------------
__global__ __launch_bounds__(256) void x_transpose(
    const float* __restrict__ x, short* __restrict__ x_bf, float* __restrict__ x_tf)
{
    __shared__ float ls[64][65];
    const int b = blockIdx.z, c0 = blockIdx.y * 64, n0 = blockIdx.x * 64;
    const int rl = threadIdx.x >> 6, ll = threadIdx.x & 63;
    #pragma unroll
    for (int it = 0; it < 16; ++it) {
        int c = rl + it * 4;
        ls[c][ll] = x[((size_t)b * 384 + c0 + c) * NPIX + n0 + ll];
    }
    __syncthreads();
    #pragma unroll
    for (int it = 0; it < 16; ++it) {
        int n = rl + it * 4;
        float v = ls[ll][n];
        size_t row = (size_t)b * NPIX + n0 + n;
        x_tf[row * 384 + c0 + ll] = v;
        x_bf[row * 384 + c0 + ll] = f2bf(v);
    }
}

// ---------------------------------------------------------------------------
// GEMM bf16 MFMA: D[row][o] = sum_k A[row][k]*Wt[o][k]. 128x128, BK=64,
// 4 waves (2x2 of 64x64), fused BN-stat atomics.
// ---------------------------------------------------------------------------
__global__ __launch_bounds__(256) void gemm_bf16(
    const short* __restrict__ A, const short* __restrict__ Wt,
    float* __restrict__ D, float* __restrict__ sums, int O, int K)
{
    __shared__ short a_s[128 * 72];
    __shared__ short w_s[128 * 72];
    const int tid = threadIdx.x;
    const int wave = tid >> 6, lane = tid & 63;
    const int l16 = lane & 15, lhi = lane >> 4;
    const int m0 = blockIdx.x * 128, o0 = blockIdx.y * 128;
    const int wm = (wave & 1) * 64, wo = (wave >> 1) * 64;

    f32x4 acc[4][4];
    #pragma unroll
    for (int i = 0; i < 4; ++i)
        #pragma unroll
        for (int j = 0; j < 4; ++j) acc[i][j] = (f32x4){0.f, 0.f, 0.f, 0.f};

    for (int k0 = 0; k0 < K; k0 += 64) {
        #pragma unroll
        for (int it = 0; it < 4; ++it) {
            int idx = tid + it * 256;
            int r = idx >> 3, ch = idx & 7;
            *(float4*)&a_s[r * 72 + ch * 8] =
                *(const float4*)&A[(size_t)(m0 + r) * K + k0 + ch * 8];
            *(float4*)&w_s[r * 72 + ch * 8] =
                *(const float4*)&Wt[(size_t)(o0 + r) * K + k0 + ch * 8];
        }
        __syncthreads();
        #pragma unroll
        for (int kb = 0; kb < 2; ++kb) {
            short8 af[4], wf[4];
            #pragma unroll
            for (int i = 0; i < 4; ++i)
                af[i] = *(const short8*)&a_s[(wm + i * 16 + l16) * 72 + kb * 32 + lhi * 8];
            #pragma unroll
            for (int j = 0; j < 4; ++j)
                wf[j] = *(const short8*)&w_s[(wo + j * 16 + l16) * 72 + kb * 32 + lhi * 8];
            #pragma unroll
            for (int i = 0; i < 4; ++i)
                #pragma unroll
                for (int j = 0; j < 4; ++j)
                    acc[i][j] = __builtin_amdgcn_mfma_f32_16x16x32_bf16(af[i], wf[j], acc[i][j], 0, 0, 0);
        }
        __syncthreads();
    }

    #pragma unroll
    for (int i = 0; i < 4; ++i) {
        #pragma unroll
        for (int r = 0; r < 4; ++r) {
            size_t row = (size_t)(m0 + wm + i * 16 + lhi * 4 + r);
            #pragma unroll
            for (int j = 0; j < 4; ++j)
                D[row * O + o0 + wo + j * 16 + l16] = acc[i][j][r];
        }
    }
    #pragma unroll
    for (int j = 0; j < 4; ++j) {
        float s1 = 0.f, s2 = 0.f;
        #pragma unroll
        for (int i = 0; i < 4; ++i)
            #pragma unroll
            for (int r = 0; r < 4; ++r) { float v = acc[i][j][r]; s1 += v; s2 += v * v; }
        s1 += __shfl_xor(s1, 16); s1 += __shfl_xor(s1, 32);
        s2 += __shfl_xor(s2, 16); s2 += __shfl_xor(s2, 32);
        if (lhi == 0) {
            int col = o0 + wo + j * 16 + l16;
            atomicAdd(&sums[col * 2], s1);
            atomicAdd(&sums[col * 2 + 1], s2);
        }
    }
}

// ---------------------------------------------------------------------------
__global__ __launch_bounds__(256) void bn_finalize(
    const float* __restrict__ sums, const float* __restrict__ gamma,
    const float* __restrict__ beta, float* __restrict__ st, int O)
{
    int ch = blockIdx.x * 256 + threadIdx.x;
    if (ch >= O) return;
    float s = sums[ch * 2], ss = sums[ch * 2 + 1];
    float mean = s * (1.0f / 8192.0f);
    float var = ss * (1.0f / 8192.0f) - mean * mean;
    float sc = gamma[ch] * rsqrtf(var + 1e-5f);
    st[ch * 2] = sc;
    st[ch * 2 + 1] = beta[ch] - mean * sc;
}

// ---------------------------------------------------------------------------
// qkv post: q/k -> qk_bf [row][512] (q pre-scaled by invsqrt(32)*log2e);
// v -> BN + transpose -> vt [(b*8+h)][128][1024]. Reads precomputed st.
// ---------------------------------------------------------------------------
__global__ __launch_bounds__(256) void qkv_post_vt(
    const float* __restrict__ raw, const float* __restrict__ st,
    short* __restrict__ qko, short* __restrict__ vto)
{
    __shared__ short ls[64][136];
    const int b = blockIdx.z, hp = blockIdx.y, n0 = blockIdx.x * 64;
    const int tid = threadIdx.x;
    const int r = tid >> 2, cg = tid & 3;
    const size_t rowbase = (size_t)(b * NPIX + n0 + r) * 1536;
    const float qs = 0.17677669529663687f * 1.4426950408889634f;  // invsqrt(32)*log2e

    {   // q/k columns
        int hh = 2 * hp + (cg >> 1);
        int chb = hh * 192 + (cg & 1) * 32;
        bool isq = (cg & 1) == 0;
        size_t orow = (size_t)(b * NPIX + n0 + r) * 512 + hp * 128 + cg * 32;
        #pragma unroll
        for (int cc = 0; cc < 8; ++cc) {
            int ch = chb + cc * 4;
            float4 v  = *(const float4*)&raw[rowbase + ch];
            float4 sa = *(const float4*)&st[ch * 2];
            float4 sb = *(const float4*)&st[ch * 2 + 4];
            float o0 = v.x * sa.x + sa.y, o1 = v.y * sa.z + sa.w;
            float o2 = v.z * sb.x + sb.y, o3 = v.w * sb.z + sb.w;
            if (isq) { o0 *= qs; o1 *= qs; o2 *= qs; o3 *= qs; }
            *(ull*)&qko[orow + cc * 4] = pack4bf(o0, o1, o2, o3);
        }
    }
    #pragma unroll
    for (int hv = 0; hv < 2; ++hv) {
        int h = 2 * hp + hv;
        __syncthreads();
        #pragma unroll
        for (int cc = 0; cc < 8; ++cc) {
            int ch = h * 192 + 64 + cg * 32 + cc * 4;
            float4 v  = *(const float4*)&raw[rowbase + ch];
            float4 sa = *(const float4*)&st[ch * 2];
            float4 sb = *(const float4*)&st[ch * 2 + 4];
            float o0 = v.x * sa.x + sa.y, o1 = v.y * sa.z + sa.w;
            float o2 = v.z * sb.x + sb.y, o3 = v.w * sb.z + sb.w;
            *(ull*)&ls[r][cg * 32 + cc * 4] = pack4bf(o0, o1, o2, o3);
        }
        __syncthreads();
        int dv = tid >> 1, nh = tid & 1;
        size_t obase = ((size_t)(b * 8 + h) * 128 + dv) * NPIX + n0 + nh * 32;
        #pragma unroll
        for (int j = 0; j < 8; ++j) {
            int n = nh * 32 + j * 4;
            ull u =  (ull)(unsigned short)ls[n][dv]
                  | ((ull)(unsigned short)ls[n + 1][dv] << 16)
                  | ((ull)(unsigned short)ls[n + 2][dv] << 32)
                  | ((ull)(unsigned short)ls[n + 3][dv] << 48);
            *(ull*)&vto[obase + j * 4] = u;
        }
    }
}

// ---------------------------------------------------------------------------
// Flash attention, swapped-QK^T, register-prefetched. 1 wave/block, 2048
// blocks XCD-swizzled. S^T = mfma(K,Q): lane l16 owns q = fq*16+l16, holds
// 16 S values (m = fm*16 + lhi*4 + r). Softmax reduce: in-lane + shfl 16/32.
// P written as 8B packs to per-wave LDS, read back as PV A-fragments.
// ---------------------------------------------------------------------------
#define ATTN_TILE(M0, KCUR, KNEXT)                                            \
{                                                                             \
    const int m0_ = (M0);                                                     \
    f32x4 s0_[4], s1_[4];                                                     \
    _Pragma("unroll")                                                         \
    for (int fm = 0; fm < 4; ++fm) {                                          \
        s0_[fm] = (f32x4){0.f, 0.f, 0.f, 0.f};                                \
        s1_[fm] = (f32x4){0.f, 0.f, 0.f, 0.f};                                \
    }                                                                         \
    _Pragma("unroll")                                                         \
    for (int fm = 0; fm < 4; ++fm) {                                          \
        s0_[fm] = __builtin_amdgcn_mfma_f32_16x16x32_bf16(KCUR[fm], qf0, s0_[fm], 0, 0, 0); \
        s1_[fm] = __builtin_amdgcn_mfma_f32_16x16x32_bf16(KCUR[fm], qf1, s1_[fm], 0, 0, 0); \
    }                                                                         \
    short8 vf_[16];                                                           \
    _Pragma("unroll")                                                         \
    for (int kc = 0; kc < 2; ++kc)                                            \
        _Pragma("unroll")                                                     \
        for (int fdv = 0; fdv < 8; ++fdv)                                     \
            vf_[kc * 8 + fdv] = *(const short8*)&vb[(size_t)(fdv * 16 + l16) * NPIX + m0_ + kc * 32 + lhi * 8]; \
    {                                                                         \
        int mn_ = (m0_ + 64) & 1023;                                          \
        _Pragma("unroll")                                                     \
        for (int fm = 0; fm < 4; ++fm)                                        \
            KNEXT[fm] = *(const short8*)&kb[(size_t)(mn_ + fm * 16 + l16) * 512 + lhi * 8]; \
    }                                                                         \
    float mx0 = fmaxf(fmaxf(s0_[0][0], s0_[0][1]), fmaxf(s0_[0][2], s0_[0][3])); \
    float mx1 = fmaxf(fmaxf(s1_[0][0], s1_[0][1]), fmaxf(s1_[0][2], s1_[0][3])); \
    _Pragma("unroll")                                                         \
    for (int fm = 1; fm < 4; ++fm) {                                          \
        mx0 = fmaxf(mx0, fmaxf(fmaxf(s0_[fm][0], s0_[fm][1]), fmaxf(s0_[fm][2], s0_[fm][3]))); \
        mx1 = fmaxf(mx1, fmaxf(fmaxf(s1_[fm][0], s1_[fm][1]), fmaxf(s1_[fm][2], s1_[fm][3]))); \
    }                                                                         \
    mx0 = fmaxf(mx0, __shfl_xor(mx0, 16)); mx0 = fmaxf(mx0, __shfl_xor(mx0, 32)); \
    mx1 = fmaxf(mx1, __shfl_xor(mx1, 16)); mx1 = fmaxf(mx1, __shfl_xor(mx1, 32)); \
    bool need_ = (mx0 > m_run0 + 11.0f) || (mx1 > m_run1 + 11.0f);            \
    if (__any(need_)) {                                                       \
        float mn0 = fmaxf(m_run0, mx0), f0 = exp2f(m_run0 - mn0);             \
        float mn1 = fmaxf(m_run1, mx1), f1 = exp2f(m_run1 - mn1);             \
        m_run0 = mn0; m_run1 = mn1; l_run0 *= f0; l_run1 *= f1;               \
        _Pragma("unroll")                                                     \
        for (int rr = 0; rr < 4; ++rr) {                                      \
            float fb0 = __shfl(f0, lhi * 4 + rr);                             \
            float fb1 = __shfl(f1, lhi * 4 + rr);                             \
            _Pragma("unroll")                                                 \
            for (int fdv = 0; fdv < 8; ++fdv) {                               \
                acc[0][fdv][rr] *= fb0;                                       \
                acc[1][fdv][rr] *= fb1;                                       \
            }                                                                 \
        }                                                                     \
    }                                                                         \
    float rs0 = 0.f, rs1 = 0.f;                                               \
    _Pragma("unroll")                                                         \
    for (int fm = 0; fm < 4; ++fm) {                                          \
        float p0 = exp2f(s0_[fm][0] - m_run0), p1 = exp2f(s0_[fm][1] - m_run0); \
        float p2 = exp2f(s0_[fm][2] - m_run0), p3 = exp2f(s0_[fm][3] - m_run0); \
        rs0 += (p0 + p1) + (p2 + p3);                                         \
        *(ull*)&pw[l16 * 72 + fm * 16 + lhi * 4] = pack4bf(p0, p1, p2, p3);   \
        float t0 = exp2f(s1_[fm][0] - m_run1), t1 = exp2f(s1_[fm][1] - m_run1); \
        float t2 = exp2f(s1_[fm][2] - m_run1), t3 = exp2f(s1_[fm][3] - m_run1); \
        rs1 += (t0 + t1) + (t2 + t3);                                         \
        *(ull*)&pw[(16 + l16) * 72 + fm * 16 + lhi * 4] = pack4bf(t0, t1, t2, t3); \
    }                                                                         \
    rs0 += __shfl_xor(rs0, 16); rs0 += __shfl_xor(rs0, 32);                   \
    rs1 += __shfl_xor(rs1, 16); rs1 += __shfl_xor(rs1, 32);                   \
    l_run0 += rs0; l_run1 += rs1;                                             \
    asm volatile("s_waitcnt lgkmcnt(0)" ::: "memory");                        \
    _Pragma("unroll")                                                         \
    for (int kc = 0; kc < 2; ++kc) {                                          \
        short8 pf0 = *(const short8*)&pw[l16 * 72 + kc * 32 + lhi * 8];       \
        short8 pf1 = *(const short8*)&pw[(16 + l16) * 72 + kc * 32 + lhi * 8]; \
        _Pragma("unroll")                                                     \
        for (int fdv = 0; fdv < 8; ++fdv) {                                   \
            acc[0][fdv] = __builtin_amdgcn_mfma_f32_16x16x32_bf16(pf0, vf_[kc * 8 + fdv], acc[0][fdv], 0, 0, 0); \
            acc[1][fdv] = __builtin_amdgcn_mfma_f32_16x16x32_bf16(pf1, vf_[kc * 8 + fdv], acc[1][fdv], 0, 0, 0); \
        }                                                                     \
    }                                                                         \
}

__global__ __launch_bounds__(64) void attn_kernel(
    const short* __restrict__ qk, const short* __restrict__ vt, short* __restrict__ outp)
{
    __shared__ short pw[32 * 72];
    const int id0 = blockIdx.x;                       // 2048
    const int swz = (id0 & 7) * 256 + (id0 >> 3);     // XCD-contiguous chunks
    const int qt = swz & 31, bh = swz >> 5;
    const int h = bh & 7, b = bh >> 3;
    const int q0 = qt * 32;
    const int lane = threadIdx.x;
    const int l16 = lane & 15, lhi = lane >> 4;

    const short* qkb = qk + (size_t)b * NPIX * 512 + h * 64;
    const short* kb  = qkb + 32;
    const short* vb  = vt + (size_t)bh * 128 * NPIX;

    short8 qf0 = *(const short8*)&qkb[(size_t)(q0 + l16) * 512 + lhi * 8];
    short8 qf1 = *(const short8*)&qkb[(size_t)(q0 + 16 + l16) * 512 + lhi * 8];

    f32x4 acc[2][8];
    #pragma unroll
    for (int i = 0; i < 2; ++i)
        #pragma unroll
        for (int j = 0; j < 8; ++j) acc[i][j] = (f32x4){0.f, 0.f, 0.f, 0.f};
    float m_run0 = -1e30f, m_run1 = -1e30f, l_run0 = 0.f, l_run1 = 0.f;

    short8 kfA[4], kfB[4];
    #pragma unroll
    for (int fm = 0; fm < 4; ++fm)
        kfA[fm] = *(const short8*)&kb[(size_t)(fm * 16 + l16) * 512 + lhi * 8];

    for (int mt = 0; mt < 16; mt += 2) {
        ATTN_TILE(mt * 64,      kfA, kfB)
        ATTN_TILE(mt * 64 + 64, kfB, kfA)
    }

    // epilogue: broadcast l to acc layout, normalize, gelu, store
    #pragma unroll
    for (int rr = 0; rr < 4; ++rr) {
        float inv0 = 1.0f / __shfl(l_run0, lhi * 4 + rr);
        float inv1 = 1.0f / __shfl(l_run1, lhi * 4 + rr);
        size_t row0 = (size_t)b * NPIX + q0 + lhi * 4 + rr;
        #pragma unroll
        for (int fdv = 0; fdv < 8; ++fdv) {
            float o0 = acc[0][fdv][rr] * inv0;
            float o1 = acc[1][fdv][rr] * inv1;
            outp[row0 * 1024 + h * 128 + fdv * 16 + l16] = f2bf(gelu_exact(o0));
            outp[(row0 + 16) * 1024 + h * 128 + fdv * 16 + l16] = f2bf(gelu_exact(o1));
        }
    }
}

// ---------------------------------------------------------------------------
__global__ __launch_bounds__(256) void x2_kernel(
    const float* __restrict__ raw, const float* __restrict__ st,
    const float* __restrict__ xtf, float* __restrict__ x2f, short* __restrict__ x2bf)
{
    int t = blockIdx.x * 256 + threadIdx.x;     // ROWS*96
    int row = t / 96, c = (t % 96) * 4;
    size_t idx = (size_t)row * 384 + c;
    float4 v  = *(const float4*)&raw[idx];
    float4 xr = *(const float4*)&xtf[idx];
    float4 sa = *(const float4*)&st[c * 2];
    float4 sb = *(const float4*)&st[c * 2 + 4];
    float o0 = xr.x + v.x * sa.x + sa.y;
    float o1 = xr.y + v.y * sa.z + sa.w;
    float o2 = xr.z + v.z * sb.x + sb.y;
    float o3 = xr.w + v.w * sb.z + sb.w;
    *(float4*)&x2f[idx] = make_float4(o0, o1, o2, o3);
    *(ull*)&x2bf[idx] = pack4bf(o0, o1, o2, o3);
}

// ---------------------------------------------------------------------------
__global__ __launch_bounds__(256) void h_kernel(
    const float* __restrict__ raw, const float* __restrict__ st, short* __restrict__ hbf)
{
    int t = blockIdx.x * 256 + threadIdx.x;     // ROWS*192
    int row = t / 192, c = (t % 192) * 4;
    size_t idx = (size_t)row * 768 + c;
    float4 v  = *(const float4*)&raw[idx];
    float4 sa = *(const float4*)&st[c * 2];
    float4 sb = *(const float4*)&st[c * 2 + 4];
    float o0 = gelu_exact(v.x * sa.x + sa.y);
    float o1 = gelu_exact(v.y * sa.z + sa.w);
    float o2 = gelu_exact(v.z * sb.x + sb.y);
    float o3 = gelu_exact(v.w * sb.z + sb.w);
    *(ull*)&hbf[idx] = pack4bf(o0, o1, o2, o3);
}

// ---------------------------------------------------------------------------
__global__ __launch_bounds__(256) void final_tr(
    const float* __restrict__ raw, const float* __restrict__ st,
    const float* __restrict__ x2f, float* __restrict__ out)
{
    __shared__ float ls[64][65];
    const int b = blockIdx.z, c0 = blockIdx.y * 64, n0 = blockIdx.x * 64;
    const int rl = threadIdx.x >> 6, ll = threadIdx.x & 63;
    const int c = c0 + ll;
    const float sc = st[c * 2], sh = st[c * 2 + 1];
    #pragma unroll
    for (int it = 0; it < 16; ++it) {
        int n = rl + it * 4;
        size_t idx = ((size_t)b * NPIX + n0 + n) * 384 + c;
        ls[n][ll] = x2f[idx] + raw[idx] * sc + sh;
    }
    __syncthreads();
    #pragma unroll
    for (int it = 0; it < 16; ++it) {
        int cr = rl + it * 4;
        out[((size_t)b * 384 + c0 + cr) * NPIX + n0 + ll] = ls[ll][cr];
    }
}

// ---------------------------------------------------------------------------
extern "C" void kernel_launch(void* const* d_in, const int* in_sizes, int n_in,
                              void* d_out, int out_size, void* d_ws, size_t ws_size,
                              hipStream_t stream)
{
    const float* x       = (const float*)d_in[0];
    const float* w_qkv   = (const float*)d_in[1];
    const float* g_qkv   = (const float*)d_in[2];
    const float* b_qkv   = (const float*)d_in[3];
    const float* w_merge = (const float*)d_in[4];
    const float* g_merge = (const float*)d_in[5];
    const float* b_merge = (const float*)d_in[6];
    const float* w_fc1   = (const float*)d_in[7];
    const float* g_fc1   = (const float*)d_in[8];
    const float* b_fc1   = (const float*)d_in[9];
    const float* w_fc2   = (const float*)d_in[10];
    const float* g_fc2   = (const float*)d_in[11];
    const float* b_fc2   = (const float*)d_in[12];
    float* out = (float*)d_out;

    char* ws = (char*)d_ws;
    short* wq_bf   = (short*)(ws + 0);            // 1,179,648 B
    short* wm_bf   = (short*)(ws + 1179648);      //   786,432
    short* wf1_bf  = (short*)(ws + 1966080);      //   589,824
    short* wf2_bf  = (short*)(ws + 2555904);      //   589,824
    short* x_bf    = (short*)(ws + 3145728);      // 6,291,456
    float* x_tf    = (float*)(ws + 9437184);      // 12,582,912
    float* qkv_raw = (float*)(ws + 22020096);     // 50,331,648 (dead after qkv_post_vt)
    short* qk_bf   = (short*)(ws + 72351744);     // 8,388,608
    short* vt      = (short*)(ws + 80740352);     // 16,777,216
    short* attn_bf = (short*)(ws + 22020096);     // 16,777,216 (reuse qkv_raw)
    float* fc1_raw = (float*)(ws + 38797312);     // 25,165,824 (reuse qkv_raw tail)
    float* fc2_raw = (float*)(ws + 22020096);     // 12,582,912 (reuse attn_bf, dead then)
    short* h_bf    = (short*)(ws + 80740352);     // 12,582,912 (reuse vt, dead then)
    float* merge_raw = (float*)(ws + 97517568);   // 12,582,912
    short* x2_bf   = (short*)(ws + 110100480);    // 6,291,456
    float* x2_f    = (float*)(ws + 116391936);    // 12,582,912
    float* sums    = (float*)(ws + 128974848);    // 24,576 B
    float* stats   = (float*)(ws + 128999424);    // 24,576 B

    float* sums_qkv = sums;
    float* sums_mg  = sums + 1536 * 2;
    float* sums_f1  = sums + (1536 + 384) * 2;
    float* sums_f2  = sums + (1536 + 384 + 768) * 2;
    float* st_qkv = stats;
    float* st_mg  = stats + 1536 * 2;
    float* st_f1  = stats + (1536 + 384) * 2;
    float* st_f2  = stats + (1536 + 384 + 768) * 2;

    hipMemsetAsync(sums, 0, 3072 * 2 * sizeof(float), stream);

    cast4<<<768, 256, 0, stream>>>(w_qkv, w_merge, w_fc1, w_fc2,
                                   wq_bf, wm_bf, wf1_bf, wf2_bf);
    x_transpose<<<dim3(16, 6, 8), 256, 0, stream>>>(x, x_bf, x_tf);

    gemm_bf16<<<dim3(64, 12), 256, 0, stream>>>(x_bf, wq_bf, qkv_raw, sums_qkv, 1536, 384);
    bn_finalize<<<6, 256, 0, stream>>>(sums_qkv, g_qkv, b_qkv, st_qkv, 1536);
    qkv_post_vt<<<dim3(16, 4, 8), 256, 0, stream>>>(qkv_raw, st_qkv, qk_bf, vt);

    attn_kernel<<<2048, 64, 0, stream>>>(qk_bf, vt, attn_bf);

    gemm_bf16<<<dim3(64, 3), 256, 0, stream>>>(attn_bf, wm_bf, merge_raw, sums_mg, 384, 1024);
    bn_finalize<<<2, 256, 0, stream>>>(sums_mg, g_merge, b_merge, st_mg, 384);
    x2_kernel<<<3072, 256, 0, stream>>>(merge_raw, st_mg, x_tf, x2_f, x2_bf);

    gemm_bf16<<<dim3(64, 6), 256, 0, stream>>>(x2_bf, wf1_bf, fc1_raw, sums_f1, 768, 384);
    bn_finalize<<<3, 256, 0, stream>>>(sums_f1, g_fc1, b_fc1, st_f1, 768);
    h_kernel<<<6144, 256, 0, stream>>>(fc1_raw, sums_f1 == sums_f1 ? st_f1 : st_f1, h_bf);

    gemm_bf16<<<dim3(64, 3), 256, 0, stream>>>(h_bf, wf2_bf, fc2_raw, sums_f2, 384, 768);
    bn_finalize<<<2, 256, 0, stream>>>(sums_f2, g_fc2, b_fc2, st_f2, 384);
    final_tr<<<dim3(16, 6, 8), 256, 0, stream>>>(fc2_raw, st_f2, x2_f, out);
}